// Round 1
// baseline (484.060 us; speedup 1.0000x reference)
//
#include <hip/hip_runtime.h>

#define ROWS_PER_BLOCK 4

// GF(256) log/antilog tables (AES poly 0x11B, generator 3), built at compile time.
struct GFTables {
    unsigned char exp_[256];  // exp_[k] = 3^k for k in 0..254; exp_[255] dummy
    unsigned char log_[256];  // log_[v] for v in 1..255; log_[0] unused
    constexpr GFTables() : exp_(), log_() {
        int v = 1;
        for (int k = 0; k < 255; ++k) {
            exp_[k] = (unsigned char)v;
            log_[v] = (unsigned char)k;
            int x2 = (v << 1) ^ ((v & 0x80) ? 0x11B : 0);  // v*2
            v = (x2 ^ v) & 0xFF;                           // v*3
        }
        exp_[255] = 1;  // never used for a real write (guarded)
        log_[0] = 0;
    }
};
__constant__ GFTables gft{};

__device__ __forceinline__ float wave_max(float v) {
#pragma unroll
    for (int off = 32; off; off >>= 1) v = fmaxf(v, __shfl_xor(v, off));
    return v;
}
__device__ __forceinline__ float wave_sum(float v) {
#pragma unroll
    for (int off = 32; off; off >>= 1) v += __shfl_xor(v, off);
    return v;
}

// One wave (64 lanes) per row. Each lane: 4 consecutive byte values on load,
// 4 consecutive dlog-domain outputs in the convolution.
extern "C" __global__ void __launch_bounds__(256, 4)
softgf256_kernel(const float* __restrict__ X, const float* __restrict__ Y,
                 float* __restrict__ OUT, int B) {
    __shared__ __align__(16) float s_pxp[ROWS_PER_BLOCK][256];  // px in dlog order, [255]=0 pad
    __shared__ __align__(16) float s_py2[ROWS_PER_BLOCK][512];  // py in dlog order, duplicated (mod-free)
    __shared__ __align__(16) float s_pz [ROWS_PER_BLOCK][256];  // log pz in byte order

    const int wave = threadIdx.x >> 6;
    const int lane = threadIdx.x & 63;
    const int row  = blockIdx.x * ROWS_PER_BLOCK + wave;
    if (row >= B) return;

    const float* xr = X + (size_t)row * 256;
    const float* yr = Y + (size_t)row * 256;
    const int m0 = lane << 2;

    // ---- softmax (probability space) ----
    float4 x4 = *(const float4*)(xr + m0);
    float4 y4 = *(const float4*)(yr + m0);

    float mx = wave_max(fmaxf(fmaxf(x4.x, x4.y), fmaxf(x4.z, x4.w)));
    float my = wave_max(fmaxf(fmaxf(y4.x, y4.y), fmaxf(y4.z, y4.w)));

    float ex0 = expf(x4.x - mx), ex1 = expf(x4.y - mx);
    float ex2 = expf(x4.z - mx), ex3 = expf(x4.w - mx);
    float ey0 = expf(y4.x - my), ey1 = expf(y4.y - my);
    float ey2 = expf(y4.z - my), ey3 = expf(y4.w - my);

    float rxs = 1.0f / wave_sum(ex0 + ex1 + ex2 + ex3);
    float rys = 1.0f / wave_sum(ey0 + ey1 + ey2 + ey3);

    float* pxp = s_pxp[wave];
    float* py2 = s_py2[wave];
    float* pz  = s_pz[wave];

    float pxv[4] = {ex0 * rxs, ex1 * rxs, ex2 * rxs, ex3 * rxs};
    float pyv[4] = {ey0 * rys, ey1 * rys, ey2 * rys, ey3 * rys};

    float px0 = 0.0f, py0 = 0.0f;
#pragma unroll
    for (int q = 0; q < 4; ++q) {
        int v = m0 + q;
        if (v == 0) {  // lane 0 only
            px0 = pxv[q]; py0 = pyv[q];
            pxp[255] = 0.0f;  // pad so the conv loop can run a full 256 steps
        } else {
            int p = gft.log_[v];
            pxp[p] = pxv[q];
            py2[p] = pyv[q];
            py2[p + 255] = pyv[q];
            if (p < 2) py2[p + 510] = pyv[q];  // fill indices 510, 511
        }
    }
    // No barrier needed: each wave reads only LDS it wrote itself (in-order DS pipe).

    // ---- cyclic convolution, dlog domain ----
    // conv[m] = sum_s pxp[s] * py2[m - s + 255], outputs m = m0 .. m0+3 per lane.
    float acc0 = 0.f, acc1 = 0.f, acc2 = 0.f, acc3 = 0.f;
    float4 H = *(const float4*)&py2[m0 + 256];  // high half of sliding window
#pragma unroll
    for (int sig = 0; sig <= 252; sig += 4) {
        float4 L = *(const float4*)&py2[m0 + 252 - sig];  // 16B-aligned, stride-1/lane
        float4 P = *(const float4*)&pxp[sig];             // uniform broadcast
        // step s = sig+d uses window LH[q+3-d], LH = {L.x..L.w, H.x..H.w}
        acc0 = fmaf(P.x, L.w, acc0);
        acc1 = fmaf(P.x, H.x, acc1);
        acc2 = fmaf(P.x, H.y, acc2);
        acc3 = fmaf(P.x, H.z, acc3);
        acc0 = fmaf(P.y, L.z, acc0);
        acc1 = fmaf(P.y, L.w, acc1);
        acc2 = fmaf(P.y, H.x, acc2);
        acc3 = fmaf(P.y, H.y, acc3);
        acc0 = fmaf(P.z, L.y, acc0);
        acc1 = fmaf(P.z, L.z, acc1);
        acc2 = fmaf(P.z, L.w, acc2);
        acc3 = fmaf(P.z, H.x, acc3);
        acc0 = fmaf(P.w, L.x, acc0);
        acc1 = fmaf(P.w, L.y, acc1);
        acc2 = fmaf(P.w, L.z, acc2);
        acc3 = fmaf(P.w, L.w, acc3);
        H = L;
    }

    // ---- epilogue: log, permute back to byte order, coalesced store ----
    float l0 = logf(acc0), l1 = logf(acc1), l2 = logf(acc2), l3 = logf(acc3);
    pz[gft.exp_[m0 + 0]] = l0;
    pz[gft.exp_[m0 + 1]] = l1;
    pz[gft.exp_[m0 + 2]] = l2;
    if (lane != 63) pz[gft.exp_[m0 + 3]] = l3;  // m=255 is a duplicate of m=0, skip
    if (lane == 0) pz[0] = logf(px0 + (1.0f - px0) * py0);

    *(float4*)(OUT + (size_t)row * 256 + m0) = *(const float4*)&pz[m0];
}

extern "C" void kernel_launch(void* const* d_in, const int* in_sizes, int n_in,
                              void* d_out, int out_size, void* d_ws, size_t ws_size,
                              hipStream_t stream) {
    const float* X = (const float*)d_in[0];
    const float* Y = (const float*)d_in[1];
    // d_in[2] (the int64 LUT) is intentionally unused: GF(256) tables are compile-time.
    float* OUT = (float*)d_out;
    const int B = in_sizes[0] / 256;
    const int blocks = (B + ROWS_PER_BLOCK - 1) / ROWS_PER_BLOCK;
    hipLaunchKernelGGL(softgf256_kernel, dim3(blocks), dim3(256), 0, stream,
                       X, Y, OUT, B);
}

// Round 7
// 72.241 us; speedup vs baseline: 6.7007x; 6.7007x over previous
//
#include <hip/hip_runtime.h>

#define ROWS_PER_BLOCK 4

// GF(256) log/antilog tables (AES poly 0x11B, generator 3), built at compile time.
struct GFTables {
    unsigned char exp_[256];  // exp_[k] = 3^k for k in 0..254; exp_[255] dummy
    unsigned char log_[256];  // log_[v] for v in 1..255; log_[0] unused
    constexpr GFTables() : exp_(), log_() {
        int v = 1;
        for (int k = 0; k < 255; ++k) {
            exp_[k] = (unsigned char)v;
            log_[v] = (unsigned char)k;
            int x2 = (v << 1) ^ ((v & 0x80) ? 0x11B : 0);  // v*2
            v = (x2 ^ v) & 0xFF;                           // v*3
        }
        exp_[255] = 1;  // never used for a real write (guarded)
        log_[0] = 0;
    }
};
__constant__ GFTables gft{};

__device__ __forceinline__ float wave_max(float v) {
#pragma unroll
    for (int off = 32; off; off >>= 1) v = fmaxf(v, __shfl_xor(v, off));
    return v;
}
__device__ __forceinline__ float wave_sum(float v) {
#pragma unroll
    for (int off = 32; off; off >>= 1) v += __shfl_xor(v, off);
    return v;
}

// One wave (64 lanes) per row. Each lane: 4 consecutive byte values on load,
// 4 consecutive dlog-domain outputs in the convolution.
extern "C" __global__ void __launch_bounds__(256, 4)
softgf256_kernel(const float* __restrict__ X, const float* __restrict__ Y,
                 float* __restrict__ OUT, int B) {
    __shared__ __align__(16) float s_pxp[ROWS_PER_BLOCK][256];  // px in dlog order, [255]=0 pad
    __shared__ __align__(16) float s_py2[ROWS_PER_BLOCK][512];  // py in dlog order, duplicated (mod-free)
    __shared__ __align__(16) float s_pz [ROWS_PER_BLOCK][256];  // log pz in byte order

    const int wave = threadIdx.x >> 6;
    const int lane = threadIdx.x & 63;
    const int row  = blockIdx.x * ROWS_PER_BLOCK + wave;
    if (row >= B) return;

    const float* xr = X + (size_t)row * 256;
    const float* yr = Y + (size_t)row * 256;
    const int m0 = lane << 2;

    // ---- softmax (probability space) ----
    float4 x4 = *(const float4*)(xr + m0);
    float4 y4 = *(const float4*)(yr + m0);

    float mx = wave_max(fmaxf(fmaxf(x4.x, x4.y), fmaxf(x4.z, x4.w)));
    float my = wave_max(fmaxf(fmaxf(y4.x, y4.y), fmaxf(y4.z, y4.w)));

    float ex0 = expf(x4.x - mx), ex1 = expf(x4.y - mx);
    float ex2 = expf(x4.z - mx), ex3 = expf(x4.w - mx);
    float ey0 = expf(y4.x - my), ey1 = expf(y4.y - my);
    float ey2 = expf(y4.z - my), ey3 = expf(y4.w - my);

    float rxs = 1.0f / wave_sum(ex0 + ex1 + ex2 + ex3);
    float rys = 1.0f / wave_sum(ey0 + ey1 + ey2 + ey3);

    float* pxp = s_pxp[wave];
    float* py2 = s_py2[wave];
    float* pz  = s_pz[wave];

    float pxv[4] = {ex0 * rxs, ex1 * rxs, ex2 * rxs, ex3 * rxs};
    float pyv[4] = {ey0 * rys, ey1 * rys, ey2 * rys, ey3 * rys};

    float px0 = 0.0f, py0 = 0.0f;
#pragma unroll
    for (int q = 0; q < 4; ++q) {
        int v = m0 + q;
        if (v == 0) {  // lane 0 only
            px0 = pxv[q]; py0 = pyv[q];
            pxp[255] = 0.0f;  // pad so the conv loop can run a full 256 steps
        } else {
            int p = gft.log_[v];
            pxp[p] = pxv[q];
            py2[p] = pyv[q];
            py2[p + 255] = pyv[q];
            if (p < 2) py2[p + 510] = pyv[q];  // fill indices 510, 511
        }
    }
    // No barrier needed: each wave reads only LDS it wrote itself (in-order DS pipe,
    // compiler inserts the lgkmcnt waits for the aliasing reads below).

    // ---- cyclic convolution, dlog domain ----
    // conv[m] = sum_s pxp[s] * py2[m - s + 255], outputs m = m0 .. m0+3 per lane.
    // NOTE: unroll capped at 4. Full unroll (64 iters) let the scheduler hoist
    // all 128 float4 LDS loads -> spill of ~2.5 KB/thread to scratch -> 1.2 GB
    // HBM scratch traffic, 435 us memory-bound (measured round 1). Partial
    // unroll keeps the sliding window register-resident.
    float acc0 = 0.f, acc1 = 0.f, acc2 = 0.f, acc3 = 0.f;
    float4 H = *(const float4*)&py2[m0 + 256];  // high half of sliding window
#pragma unroll 4
    for (int sig = 0; sig <= 252; sig += 4) {
        float4 L = *(const float4*)&py2[m0 + 252 - sig];  // 16B-aligned, stride-1/lane
        float4 P = *(const float4*)&pxp[sig];             // uniform broadcast
        // step s = sig+d uses window LH[q+3-d], LH = {L.x..L.w, H.x..H.w}
        acc0 = fmaf(P.x, L.w, acc0);
        acc1 = fmaf(P.x, H.x, acc1);
        acc2 = fmaf(P.x, H.y, acc2);
        acc3 = fmaf(P.x, H.z, acc3);
        acc0 = fmaf(P.y, L.z, acc0);
        acc1 = fmaf(P.y, L.w, acc1);
        acc2 = fmaf(P.y, H.x, acc2);
        acc3 = fmaf(P.y, H.y, acc3);
        acc0 = fmaf(P.z, L.y, acc0);
        acc1 = fmaf(P.z, L.z, acc1);
        acc2 = fmaf(P.z, L.w, acc2);
        acc3 = fmaf(P.z, H.x, acc3);
        acc0 = fmaf(P.w, L.x, acc0);
        acc1 = fmaf(P.w, L.y, acc1);
        acc2 = fmaf(P.w, L.z, acc2);
        acc3 = fmaf(P.w, L.w, acc3);
        H = L;
    }

    // ---- epilogue: log, permute back to byte order, coalesced store ----
    float l0 = logf(acc0), l1 = logf(acc1), l2 = logf(acc2), l3 = logf(acc3);
    pz[gft.exp_[m0 + 0]] = l0;
    pz[gft.exp_[m0 + 1]] = l1;
    pz[gft.exp_[m0 + 2]] = l2;
    if (lane != 63) pz[gft.exp_[m0 + 3]] = l3;  // m=255 is a duplicate of m=0, skip
    if (lane == 0) pz[0] = logf(px0 + (1.0f - px0) * py0);

    *(float4*)(OUT + (size_t)row * 256 + m0) = *(const float4*)&pz[m0];
}

extern "C" void kernel_launch(void* const* d_in, const int* in_sizes, int n_in,
                              void* d_out, int out_size, void* d_ws, size_t ws_size,
                              hipStream_t stream) {
    const float* X = (const float*)d_in[0];
    const float* Y = (const float*)d_in[1];
    // d_in[2] (the int64 LUT) is intentionally unused: GF(256) tables are compile-time.
    float* OUT = (float*)d_out;
    const int B = in_sizes[0] / 256;
    const int blocks = (B + ROWS_PER_BLOCK - 1) / ROWS_PER_BLOCK;
    hipLaunchKernelGGL(softgf256_kernel, dim3(blocks), dim3(256), 0, stream,
                       X, Y, OUT, B);
}